// Round 9
// baseline (473.410 us; speedup 1.0000x reference)
//
#include <hip/hip_runtime.h>

#define N_NODES 50000
#define N_EDGES 1000000
#define N_ETYPES 3
#define NB 782                     // ceil(50000/64) buckets of 64 dst nodes
#define TOTB (N_ETYPES * NB)       // 2346 bucket bins
#define EPB 32768                  // edges per fill block (two-pass, no reg staging)
#define FB  ((N_EDGES + EPB - 1) / EPB)   // 31 fill blocks per etype -> chain depth 31
#define GCAP 2048                  // fixed record slots per bucket (mean 1280, sd 36: +21 sigma)

typedef _Float16 f16x8 __attribute__((ext_vector_type(8)));
typedef float f32x4 __attribute__((ext_vector_type(4)));

// ---------- Kernel 0: W[e][k][n] fp32 -> Wt[e][n][k] fp16 ----------
__global__ void k_prep_w(const float* __restrict__ W, _Float16* __restrict__ Wt) {
    int e  = blockIdx.y;
    int id = blockIdx.x * blockDim.x + threadIdx.x;   // 0..32767
    int k  = id >> 7;
    int n  = id & 127;
    Wt[(size_t)e * 32768 + (size_t)n * 256 + k] =
        (_Float16)W[(size_t)e * 32768 + (size_t)k * 128 + n];
}

// ---------- Kernel 1: Wh[e] = fp16( x @ W[e] + b[e] )  (MFMA, no LDS) ----------
// A-path reads x in f32 and converts in-register (round-0 verified code) —
// k_prep_x deleted; total traffic identical, one fewer kernel+gap.
// 128-row blocks: grid 391x3 = 4.6 waves/SIMD. Fragment maps (m89/m91-verified,
// bit-identical history): A[m=lane&15][k=quad*8+j], B^T row = lane&15,
// D: col=lane&15, row=quad*4+reg.
__global__ __launch_bounds__(256) void k_gemm(
    const float* __restrict__ x,             // [N,256] fp32
    const _Float16* __restrict__ Wt,         // [3][128][256] fp16 (W^T)
    const float* __restrict__ b,             // [3][128] fp32
    unsigned short* __restrict__ Wh)         // [3][N][128] fp16 bits
{
    const int e    = blockIdx.y;
    const int tid  = threadIdx.x;
    const int lane = tid & 63;
    const int w    = tid >> 6;       // wave 0..3
    const int q    = lane >> 4;      // quad 0..3
    const int c    = lane & 15;      // m for A, n for B/D
    const int rowBase = blockIdx.x * 128;
    const _Float16* Bt = Wt + (size_t)e * 32768;   // [128][256]

    f32x4 acc[2][8];
    #pragma unroll
    for (int mt = 0; mt < 2; ++mt)
        #pragma unroll
        for (int nt = 0; nt < 8; ++nt)
            acc[mt][nt] = (f32x4){0.f, 0.f, 0.f, 0.f};

    int arow[2];
    #pragma unroll
    for (int mt = 0; mt < 2; ++mt) {
        int r = rowBase + w * 32 + mt * 16 + c;
        arow[mt] = (r < N_NODES) ? r : (N_NODES - 1);   // clamp; discarded at store
    }

    #pragma unroll
    for (int ks = 0; ks < 8; ++ks) {           // K = 256 = 8 * 32
        f16x8 afrag[2];
        #pragma unroll
        for (int mt = 0; mt < 2; ++mt) {
            const float* xp = x + (size_t)arow[mt] * 256 + ks * 32 + q * 8;
            f32x4 lo = *(const f32x4*)xp;
            f32x4 hi = *(const f32x4*)(xp + 4);
            f16x8 af;
            #pragma unroll
            for (int j = 0; j < 4; ++j) {
                af[j]     = (_Float16)lo[j];
                af[j + 4] = (_Float16)hi[j];
            }
            afrag[mt] = af;
        }
        #pragma unroll
        for (int nt = 0; nt < 8; ++nt) {
            f16x8 bfrag = *(const f16x8*)(Bt + (size_t)(nt * 16 + c) * 256 + ks * 32 + q * 8);
            #pragma unroll
            for (int mt = 0; mt < 2; ++mt)
                acc[mt][nt] = __builtin_amdgcn_mfma_f32_16x16x32_f16(
                    afrag[mt], bfrag, acc[mt][nt], 0, 0, 0);
        }
    }

    const size_t whBase = (size_t)e * N_NODES * 128;
    #pragma unroll
    for (int nt = 0; nt < 8; ++nt) {
        float bias = b[e * 128 + nt * 16 + c];
        #pragma unroll
        for (int mt = 0; mt < 2; ++mt) {
            int baseRow = rowBase + w * 32 + mt * 16 + q * 4;
            #pragma unroll
            for (int r = 0; r < 4; ++r) {
                int row = baseRow + r;
                if (row < N_NODES) {
                    float v = acc[mt][nt][r] + bias;
                    Wh[whBase + (size_t)row * 128 + nt * 16 + c] =
                        __builtin_bit_cast(unsigned short, (_Float16)v);
                }
            }
        }
    }
}

// ---------- Two-pass bucket fill: 31-deep chains (was 123) ----------
// Round-8 post-mortem: 123 co-resident blocks x 1 atomicAdd each per bucket =
// 123-deep same-address RMW chains (~55us at round-2's ~450ns/link). Now 31
// fat blocks: pass1 LDS-histogram (no reg staging), ONE reservation atomic per
// (block,bucket) -> chain depth 31 (~14us), pass2 re-reads edges and places
// records (any within-bucket permutation is valid). gcur ends as exact counts.
__global__ __launch_bounds__(256) void k_fill(
    const int* __restrict__ src, const int* __restrict__ dst,
    int* __restrict__ gcur, unsigned* __restrict__ grec)
{
    __shared__ int lcnt[NB];
    __shared__ int lbase[NB];
    const int e   = blockIdx.y;
    const int tid = threadIdx.x;
    const int beg = blockIdx.x * EPB;
    int end = beg + EPB; if (end > N_EDGES) end = N_EDGES;
    const int* se = src + (size_t)e * N_EDGES;
    const int* de = dst + (size_t)e * N_EDGES;

    for (int j = tid; j < NB; j += 256) lcnt[j] = 0;
    __syncthreads();
    #pragma unroll 4
    for (int i = beg + tid; i < end; i += 256)
        atomicAdd(&lcnt[__builtin_nontemporal_load(de + i) >> 6], 1);
    __syncthreads();
    for (int j = tid; j < NB; j += 256) {
        int c = lcnt[j];
        lbase[j] = c ? atomicAdd(&gcur[e * NB + j], c) : 0;
        lcnt[j] = 0;
    }
    __syncthreads();
    #pragma unroll 4
    for (int i = beg + tid; i < end; i += 256) {
        int s = __builtin_nontemporal_load(se + i);
        int d = __builtin_nontemporal_load(de + i);
        int b = d >> 6;
        int lpos = atomicAdd(&lcnt[b], 1);
        int pos = lbase[b] + lpos;
        if (pos < GCAP)                        // defensive; never trips (+21 sigma)
            grec[(size_t)(e * NB + b) * GCAP + pos] =
                (unsigned)s | ((unsigned)(d & 63) << 16);
    }
}

// ---------- Fused bucket sort + gather (UNCHANGED round-8 control, 123us) ----------
// Paired-row dwordx2 loads: lanes 0-31 even record, 32-63 odd, 8B/lane -> one
// VMEM fetches TWO rows -> 16 rows in flight. Cross-half combine: 4x
// shfl_xor(32); lanes<32 write float4 (512B/node, NT store).
__global__ __launch_bounds__(256) void k_bagg(
    const int* __restrict__ cnt_b, const unsigned* __restrict__ grec,
    const unsigned short* __restrict__ Wh, float* __restrict__ out)
{
    __shared__ unsigned       rec_s[GCAP];   // 8 KB
    __shared__ unsigned short nbr_s[GCAP];   // 4 KB
    __shared__ int ndeg[64], ncur[64], nstart[64];
    const int e    = blockIdx.y;
    const int bx   = blockIdx.x;
    const int tid  = threadIdx.x;
    const int lane = tid & 63;
    const int w    = tid >> 6;
    const int half = lane >> 5;             // 0: even record, 1: odd record
    const int sub  = lane & 31;
    const int eb   = e * NB + bx;
    const size_t beg = (size_t)eb * GCAP;
    int m = cnt_b[eb];
    if (m > GCAP) m = GCAP;                  // defensive; never trips
    const unsigned* base = (const unsigned*)Wh + (size_t)e * N_NODES * 64; // 64 u32/row

    if (tid < 64) ndeg[tid] = 0;
    __syncthreads();

    // pass 1: stage records + degree histogram (single global read of grec)
    for (int i = tid; i < m; i += 256) {
        unsigned r = __builtin_nontemporal_load(grec + beg + i);
        rec_s[i] = r;
        atomicAdd(&ndeg[r >> 16], 1);
    }
    __syncthreads();
    if (tid < 64) {                     // wave 0: exclusive scan of 64 degrees
        int v = ndeg[tid];
        int s = v;
        #pragma unroll
        for (int d = 1; d < 64; d <<= 1) {
            int t = __shfl_up(s, d);
            if (tid >= d) s += t;
        }
        int excl = s - v;
        nstart[tid] = excl;
        ncur[tid]   = excl;
    }
    __syncthreads();
    // pass 2: counting-sort scatter into LDS neighbor list
    for (int i = tid; i < m; i += 256) {
        unsigned r = rec_s[i];
        int p = atomicAdd(&ncur[r >> 16], 1);
        nbr_s[p] = (unsigned short)(r & 0xFFFFu);
    }
    __syncthreads();

    // gather: wave w owns nodes w*16..w*16+15
    for (int t = 0; t < 16; ++t) {
        int node = w * 16 + t;
        int st = nstart[node];
        int dg = ndeg[node];
        float a0 = 0.f, a1 = 0.f, a2 = 0.f, a3 = 0.f;
        for (int c0 = 0; c0 < dg; c0 += 64) {
            int mm = dg - c0; if (mm > 64) mm = 64;
            int idx = (c0 + lane < dg) ? (int)nbr_s[st + c0 + lane] : 0;
            int fullp = mm >> 1;                 // complete pairs
            int p = 0;
            for (; p + 8 <= fullp; p += 8) {     // 16 rows in flight
                uint2 u[8];
                #pragma unroll
                for (int k = 0; k < 8; ++k) {
                    int r0 = 2 * (p + k);
                    int s0 = __builtin_amdgcn_readlane(idx, r0);
                    int s1 = __builtin_amdgcn_readlane(idx, r0 + 1);
                    int s  = half ? s1 : s0;
                    u[k] = *(const uint2*)(base + (size_t)s * 64 + (sub << 1));
                }
                #pragma unroll
                for (int k = 0; k < 8; ++k) {
                    a0 += (float)__builtin_bit_cast(_Float16, (unsigned short)(u[k].x & 0xFFFFu));
                    a1 += (float)__builtin_bit_cast(_Float16, (unsigned short)(u[k].x >> 16));
                    a2 += (float)__builtin_bit_cast(_Float16, (unsigned short)(u[k].y & 0xFFFFu));
                    a3 += (float)__builtin_bit_cast(_Float16, (unsigned short)(u[k].y >> 16));
                }
            }
            if (2 * p < mm) {                    // masked 8-pair tail
                uint2 u[8];
                #pragma unroll
                for (int k = 0; k < 8; ++k) {
                    int r0 = 2 * (p + k);
                    int r0c = (r0     < mm) ? r0     : 0;
                    int r1c = (r0 + 1 < mm) ? r0 + 1 : 0;
                    int s0 = __builtin_amdgcn_readlane(idx, r0c);
                    int s1 = __builtin_amdgcn_readlane(idx, r1c);
                    int s  = half ? s1 : s0;
                    u[k] = *(const uint2*)(base + (size_t)s * 64 + (sub << 1));
                }
                #pragma unroll
                for (int k = 0; k < 8; ++k) {
                    if (2 * (p + k) + half < mm) {
                        a0 += (float)__builtin_bit_cast(_Float16, (unsigned short)(u[k].x & 0xFFFFu));
                        a1 += (float)__builtin_bit_cast(_Float16, (unsigned short)(u[k].x >> 16));
                        a2 += (float)__builtin_bit_cast(_Float16, (unsigned short)(u[k].y & 0xFFFFu));
                        a3 += (float)__builtin_bit_cast(_Float16, (unsigned short)(u[k].y >> 16));
                    }
                }
            }
        }
        // combine even/odd halves: lane L += lane L^32
        a0 += __shfl_xor(a0, 32);
        a1 += __shfl_xor(a1, 32);
        a2 += __shfl_xor(a2, 32);
        a3 += __shfl_xor(a3, 32);
        int n = bx * 64 + node;
        if (half == 0 && n < N_NODES) {
            float inv = (dg > 0) ? (1.0f / (float)dg) : 0.f;
            f32x4 o = {a0 * inv, a1 * inv, a2 * inv, a3 * inv};
            __builtin_nontemporal_store(o, (f32x4*)(out + (size_t)n * 384 + e * 128 + (sub << 2)));
        }
    }
}

// ---------- launch ----------
extern "C" void kernel_launch(void* const* d_in, const int* in_sizes, int n_in,
                              void* d_out, int out_size, void* d_ws, size_t ws_size,
                              hipStream_t stream) {
    const float* x    = (const float*)d_in[0];
    const int*   esrc = (const int*)d_in[1];
    const int*   edst = (const int*)d_in[2];
    const float* W    = (const float*)d_in[3];
    const float* bias = (const float*)d_in[4];
    float*       out  = (float*)d_out;            // fp32 output [N,3,128]

    char* ws = (char*)d_ws;
    _Float16*       Wt  = (_Float16*)ws;                          //    196,608 B
    unsigned short* Wh  = (unsigned short*)(ws + 196608);         // 38,400,000 B
    unsigned* grec = (unsigned*)(ws + 38596608);                  // 19,218,432 B (TOTB*GCAP*4)
    int* gcur      = (int*)(ws + 57815040);                       //      9,472 B

    hipMemsetAsync(gcur, 0, TOTB * sizeof(int), stream);

    k_prep_w<<<dim3(128, 3), 256, 0, stream>>>(W, Wt);
    k_fill<<<dim3(FB, 3), 256, 0, stream>>>(esrc, edst, gcur, grec);
    k_gemm<<<dim3(391, 3), 256, 0, stream>>>(x, Wt, bias, Wh);
    k_bagg<<<dim3(NB, 3), 256, 0, stream>>>(gcur, grec, Wh, out);
}

// Round 10
// 338.242 us; speedup vs baseline: 1.3996x; 1.3996x over previous
//
#include <hip/hip_runtime.h>

#define N_NODES 50000
#define N_EDGES 1000000
#define N_ETYPES 3
#define NB 782                     // ceil(50000/64) buckets of 64 dst nodes
#define TOTB (N_ETYPES * NB)       // 2346 bucket bins
#define EPB 8192                   // edges per fill block (round-8 verified)
#define EPT 32                     // edges per thread (EPB/256)
#define FB  ((N_EDGES + EPB - 1) / EPB)   // 123 fill blocks per etype
#define GEMMB 391                  // gemm blocks per etype (128 rows each)
#define GCAP 2048                  // fixed record slots per bucket (mean 1280, sd 36: +21 sigma)

typedef _Float16 f16x8 __attribute__((ext_vector_type(8)));
typedef float f32x4 __attribute__((ext_vector_type(4)));

// ---------- Kernel 0: W[e][k][n] fp32 -> Wt[e][n][k] fp16 ----------
__global__ void k_prep_w(const float* __restrict__ W, _Float16* __restrict__ Wt) {
    int e  = blockIdx.y;
    int id = blockIdx.x * blockDim.x + threadIdx.x;   // 0..32767
    int k  = id >> 7;
    int n  = id & 127;
    Wt[(size_t)e * 32768 + (size_t)n * 256 + k] =
        (_Float16)W[(size_t)e * 32768 + (size_t)k * 128 + n];
}

// ---------- Fused gemm + fill: independent dataflows overlapped on the CUs ----
// Round-9 post-mortem: two-pass fill at 93 blocks = 3.65% occupancy = 162us
// (parallelism-bound, NOT chain-bound). Reverted to round-8's 369-block
// reg-staged fill, and fused it with gemm via blockIdx branch so fill's
// latency-bound atomic chains hide under gemm's MFMA/VMEM instead of
// serializing after it. Both branches are byte-identical to verified kernels.
__global__ __launch_bounds__(256) void k_gf(
    const float* __restrict__ x,             // [N,256] fp32
    const _Float16* __restrict__ Wt,         // [3][128][256] fp16 (W^T)
    const float* __restrict__ b,             // [3][128] fp32
    unsigned short* __restrict__ Wh,         // [3][N][128] fp16 bits
    const int* __restrict__ src, const int* __restrict__ dst,
    int* __restrict__ gcur, unsigned* __restrict__ grec)
{
    const int e   = blockIdx.y;
    const int tid = threadIdx.x;

    if (blockIdx.x < GEMMB) {
        // ================= GEMM branch (round-9 verified code) =================
        // Fragment maps (m89/m91-verified, bit-identical history):
        //   A[m=lane&15][k=quad*8+j], B^T row = lane&15, D: col=lane&15, row=quad*4+reg.
        const int lane = tid & 63;
        const int w    = tid >> 6;       // wave 0..3
        const int q    = lane >> 4;      // quad 0..3
        const int c    = lane & 15;      // m for A, n for B/D
        const int rowBase = blockIdx.x * 128;
        const _Float16* Bt = Wt + (size_t)e * 32768;   // [128][256]

        f32x4 acc[2][8];
        #pragma unroll
        for (int mt = 0; mt < 2; ++mt)
            #pragma unroll
            for (int nt = 0; nt < 8; ++nt)
                acc[mt][nt] = (f32x4){0.f, 0.f, 0.f, 0.f};

        int arow[2];
        #pragma unroll
        for (int mt = 0; mt < 2; ++mt) {
            int r = rowBase + w * 32 + mt * 16 + c;
            arow[mt] = (r < N_NODES) ? r : (N_NODES - 1);   // clamp; discarded at store
        }

        #pragma unroll
        for (int ks = 0; ks < 8; ++ks) {           // K = 256 = 8 * 32
            f16x8 afrag[2];
            #pragma unroll
            for (int mt = 0; mt < 2; ++mt) {
                const float* xp = x + (size_t)arow[mt] * 256 + ks * 32 + q * 8;
                f32x4 lo = *(const f32x4*)xp;
                f32x4 hi = *(const f32x4*)(xp + 4);
                f16x8 af;
                #pragma unroll
                for (int j = 0; j < 4; ++j) {
                    af[j]     = (_Float16)lo[j];
                    af[j + 4] = (_Float16)hi[j];
                }
                afrag[mt] = af;
            }
            #pragma unroll
            for (int nt = 0; nt < 8; ++nt) {
                f16x8 bfrag = *(const f16x8*)(Bt + (size_t)(nt * 16 + c) * 256 + ks * 32 + q * 8);
                #pragma unroll
                for (int mt = 0; mt < 2; ++mt)
                    acc[mt][nt] = __builtin_amdgcn_mfma_f32_16x16x32_f16(
                        afrag[mt], bfrag, acc[mt][nt], 0, 0, 0);
            }
        }

        const size_t whBase = (size_t)e * N_NODES * 128;
        #pragma unroll
        for (int nt = 0; nt < 8; ++nt) {
            float bias = b[e * 128 + nt * 16 + c];
            #pragma unroll
            for (int mt = 0; mt < 2; ++mt) {
                int baseRow = rowBase + w * 32 + mt * 16 + q * 4;
                #pragma unroll
                for (int r = 0; r < 4; ++r) {
                    int row = baseRow + r;
                    if (row < N_NODES) {
                        float v = acc[mt][nt][r] + bias;
                        Wh[whBase + (size_t)row * 128 + nt * 16 + c] =
                            __builtin_bit_cast(unsigned short, (_Float16)v);
                    }
                }
            }
        }
    } else {
        // ================= FILL branch (round-8 verified code) =================
        // Per-edge LDS atomics assign local positions; ONE global atomicAdd per
        // (block,bucket) reserves a range; bucket-grouped writes stay L2-resident.
        __shared__ int lcnt[NB];
        __shared__ int lbase[NB];
        const int beg = (blockIdx.x - GEMMB) * EPB;
        const int* se = src + (size_t)e * N_EDGES;
        const int* de = dst + (size_t)e * N_EDGES;

        for (int j = tid; j < NB; j += 256) lcnt[j] = 0;
        __syncthreads();

        unsigned rec[EPT];
        int      bl [EPT];
        #pragma unroll
        for (int k = 0; k < EPT; ++k) {
            int i = beg + k * 256 + tid;           // coalesced
            if (i < N_EDGES) {
                int s = __builtin_nontemporal_load(se + i);
                int d = __builtin_nontemporal_load(de + i);
                int bb = d >> 6;
                int lpos = atomicAdd(&lcnt[bb], 1);
                rec[k] = (unsigned)s | ((unsigned)(d & 63) << 16);
                bl[k]  = bb | (lpos << 10);        // b<1024 (10b), lpos<8192 (13b)
            } else {
                bl[k] = -1;
            }
        }
        __syncthreads();
        for (int j = tid; j < NB; j += 256) {
            int c = lcnt[j];
            lbase[j] = c ? atomicAdd(&gcur[e * NB + j], c) : 0;
        }
        __syncthreads();
        #pragma unroll
        for (int k = 0; k < EPT; ++k) {
            if (bl[k] >= 0) {
                int bb   = bl[k] & 1023;
                int pos  = lbase[bb] + (bl[k] >> 10);
                if (pos < GCAP)                    // defensive; never trips (+21 sigma)
                    grec[(size_t)(e * NB + bb) * GCAP + pos] = rec[k];
            }
        }
    }
}

// ---------- Fused bucket sort + gather (UNCHANGED round-8 control, 123us) ----------
// Paired-row dwordx2 loads: lanes 0-31 even record, 32-63 odd, 8B/lane -> one
// VMEM fetches TWO rows -> 16 rows in flight. Cross-half combine: 4x
// shfl_xor(32); lanes<32 write float4 (512B/node, NT store).
__global__ __launch_bounds__(256) void k_bagg(
    const int* __restrict__ cnt_b, const unsigned* __restrict__ grec,
    const unsigned short* __restrict__ Wh, float* __restrict__ out)
{
    __shared__ unsigned       rec_s[GCAP];   // 8 KB
    __shared__ unsigned short nbr_s[GCAP];   // 4 KB
    __shared__ int ndeg[64], ncur[64], nstart[64];
    const int e    = blockIdx.y;
    const int bx   = blockIdx.x;
    const int tid  = threadIdx.x;
    const int lane = tid & 63;
    const int w    = tid >> 6;
    const int half = lane >> 5;             // 0: even record, 1: odd record
    const int sub  = lane & 31;
    const int eb   = e * NB + bx;
    const size_t beg = (size_t)eb * GCAP;
    int m = cnt_b[eb];
    if (m > GCAP) m = GCAP;                  // defensive; never trips
    const unsigned* base = (const unsigned*)Wh + (size_t)e * N_NODES * 64; // 64 u32/row

    if (tid < 64) ndeg[tid] = 0;
    __syncthreads();

    // pass 1: stage records + degree histogram (single global read of grec)
    for (int i = tid; i < m; i += 256) {
        unsigned r = __builtin_nontemporal_load(grec + beg + i);
        rec_s[i] = r;
        atomicAdd(&ndeg[r >> 16], 1);
    }
    __syncthreads();
    if (tid < 64) {                     // wave 0: exclusive scan of 64 degrees
        int v = ndeg[tid];
        int s = v;
        #pragma unroll
        for (int d = 1; d < 64; d <<= 1) {
            int t = __shfl_up(s, d);
            if (tid >= d) s += t;
        }
        int excl = s - v;
        nstart[tid] = excl;
        ncur[tid]   = excl;
    }
    __syncthreads();
    // pass 2: counting-sort scatter into LDS neighbor list
    for (int i = tid; i < m; i += 256) {
        unsigned r = rec_s[i];
        int p = atomicAdd(&ncur[r >> 16], 1);
        nbr_s[p] = (unsigned short)(r & 0xFFFFu);
    }
    __syncthreads();

    // gather: wave w owns nodes w*16..w*16+15
    for (int t = 0; t < 16; ++t) {
        int node = w * 16 + t;
        int st = nstart[node];
        int dg = ndeg[node];
        float a0 = 0.f, a1 = 0.f, a2 = 0.f, a3 = 0.f;
        for (int c0 = 0; c0 < dg; c0 += 64) {
            int mm = dg - c0; if (mm > 64) mm = 64;
            int idx = (c0 + lane < dg) ? (int)nbr_s[st + c0 + lane] : 0;
            int fullp = mm >> 1;                 // complete pairs
            int p = 0;
            for (; p + 8 <= fullp; p += 8) {     // 16 rows in flight
                uint2 u[8];
                #pragma unroll
                for (int k = 0; k < 8; ++k) {
                    int r0 = 2 * (p + k);
                    int s0 = __builtin_amdgcn_readlane(idx, r0);
                    int s1 = __builtin_amdgcn_readlane(idx, r0 + 1);
                    int s  = half ? s1 : s0;
                    u[k] = *(const uint2*)(base + (size_t)s * 64 + (sub << 1));
                }
                #pragma unroll
                for (int k = 0; k < 8; ++k) {
                    a0 += (float)__builtin_bit_cast(_Float16, (unsigned short)(u[k].x & 0xFFFFu));
                    a1 += (float)__builtin_bit_cast(_Float16, (unsigned short)(u[k].x >> 16));
                    a2 += (float)__builtin_bit_cast(_Float16, (unsigned short)(u[k].y & 0xFFFFu));
                    a3 += (float)__builtin_bit_cast(_Float16, (unsigned short)(u[k].y >> 16));
                }
            }
            if (2 * p < mm) {                    // masked 8-pair tail
                uint2 u[8];
                #pragma unroll
                for (int k = 0; k < 8; ++k) {
                    int r0 = 2 * (p + k);
                    int r0c = (r0     < mm) ? r0     : 0;
                    int r1c = (r0 + 1 < mm) ? r0 + 1 : 0;
                    int s0 = __builtin_amdgcn_readlane(idx, r0c);
                    int s1 = __builtin_amdgcn_readlane(idx, r1c);
                    int s  = half ? s1 : s0;
                    u[k] = *(const uint2*)(base + (size_t)s * 64 + (sub << 1));
                }
                #pragma unroll
                for (int k = 0; k < 8; ++k) {
                    if (2 * (p + k) + half < mm) {
                        a0 += (float)__builtin_bit_cast(_Float16, (unsigned short)(u[k].x & 0xFFFFu));
                        a1 += (float)__builtin_bit_cast(_Float16, (unsigned short)(u[k].x >> 16));
                        a2 += (float)__builtin_bit_cast(_Float16, (unsigned short)(u[k].y & 0xFFFFu));
                        a3 += (float)__builtin_bit_cast(_Float16, (unsigned short)(u[k].y >> 16));
                    }
                }
            }
        }
        // combine even/odd halves: lane L += lane L^32
        a0 += __shfl_xor(a0, 32);
        a1 += __shfl_xor(a1, 32);
        a2 += __shfl_xor(a2, 32);
        a3 += __shfl_xor(a3, 32);
        int n = bx * 64 + node;
        if (half == 0 && n < N_NODES) {
            float inv = (dg > 0) ? (1.0f / (float)dg) : 0.f;
            f32x4 o = {a0 * inv, a1 * inv, a2 * inv, a3 * inv};
            __builtin_nontemporal_store(o, (f32x4*)(out + (size_t)n * 384 + e * 128 + (sub << 2)));
        }
    }
}

// ---------- launch ----------
extern "C" void kernel_launch(void* const* d_in, const int* in_sizes, int n_in,
                              void* d_out, int out_size, void* d_ws, size_t ws_size,
                              hipStream_t stream) {
    const float* x    = (const float*)d_in[0];
    const int*   esrc = (const int*)d_in[1];
    const int*   edst = (const int*)d_in[2];
    const float* W    = (const float*)d_in[3];
    const float* bias = (const float*)d_in[4];
    float*       out  = (float*)d_out;            // fp32 output [N,3,128]

    char* ws = (char*)d_ws;
    _Float16*       Wt  = (_Float16*)ws;                          //    196,608 B
    unsigned short* Wh  = (unsigned short*)(ws + 196608);         // 38,400,000 B
    unsigned* grec = (unsigned*)(ws + 38596608);                  // 19,218,432 B (TOTB*GCAP*4)
    int* gcur      = (int*)(ws + 57815040);                       //      9,472 B

    hipMemsetAsync(gcur, 0, TOTB * sizeof(int), stream);

    k_prep_w<<<dim3(128, 3), 256, 0, stream>>>(W, Wt);
    k_gf<<<dim3(GEMMB + FB, 3), 256, 0, stream>>>(x, Wt, bias, Wh, esrc, edst, gcur, grec);
    k_bagg<<<dim3(NB, 3), 256, 0, stream>>>(gcur, grec, Wh, out);
}

// Round 11
// 324.177 us; speedup vs baseline: 1.4603x; 1.0434x over previous
//
#include <hip/hip_runtime.h>

#define N_NODES 50000
#define N_EDGES 1000000
#define N_ETYPES 3
#define NB 782                     // ceil(50000/64) buckets of 64 dst nodes
#define TOTB (N_ETYPES * NB)       // 2346 bucket bins
#define EPB 8192                   // edges per fill block (round-8 verified)
#define EPT 32                     // edges per thread (EPB/256)
#define FB  ((N_EDGES + EPB - 1) / EPB)   // 123 fill blocks per etype
#define GEMMB 391                  // gemm blocks per etype (128 rows each)
#define GEMM_IDS 1176              // 49 groups * 24 ids (x-row trio co-located per XCD)
#define FILLB (FB * N_ETYPES)      // 369
#define GCAP 2048                  // fixed record slots per bucket (mean 1280, sd 36: +21 sigma)

typedef _Float16 f16x8 __attribute__((ext_vector_type(8)));
typedef float f32x4 __attribute__((ext_vector_type(4)));

// ---------- Kernel 0: W transpose->fp16; block (0,0) also zeroes gcur ----------
__global__ void k_prep_w(const float* __restrict__ W, _Float16* __restrict__ Wt,
                         int* __restrict__ gcur) {
    int e  = blockIdx.y;
    int id = blockIdx.x * blockDim.x + threadIdx.x;   // 0..32767
    int k  = id >> 7;
    int n  = id & 127;
    Wt[(size_t)e * 32768 + (size_t)n * 256 + k] =
        (_Float16)W[(size_t)e * 32768 + (size_t)k * 128 + n];
    if (blockIdx.x == 0 && e == 0)
        for (int j = threadIdx.x; j < TOTB; j += 256) gcur[j] = 0;
}

// ---------- Fused gemm + fill (round-10 verified branches, XCD-aware ids) ----
// gemm ids: id=24g+8e+r -> bx=8g+r. The three etype-blocks sharing rowBase are
// ids {24g+r, 24g+8+r, 24g+16+r} == r (mod 8) -> same XCD under round-robin
// dispatch -> x rows fetched once per XCD instead of 3x.
__global__ __launch_bounds__(256) void k_gf(
    const float* __restrict__ x,             // [N,256] fp32
    const _Float16* __restrict__ Wt,         // [3][128][256] fp16 (W^T)
    const float* __restrict__ b,             // [3][128] fp32
    unsigned short* __restrict__ Wh,         // [3][N][128] fp16 bits
    const int* __restrict__ src, const int* __restrict__ dst,
    int* __restrict__ gcur, unsigned* __restrict__ grec)
{
    const int tid = threadIdx.x;

    if (blockIdx.x < GEMM_IDS) {
        // ================= GEMM branch (verified code; remapped ids) ============
        const int id  = blockIdx.x;
        const int g   = id / 24;
        const int rem = id - g * 24;
        const int e   = rem >> 3;
        const int bx  = g * 8 + (rem & 7);
        if (bx >= GEMMB) return;             // 3 idle ids; no syncthreads here
        // Fragment maps (m89/m91-verified, bit-identical history):
        //   A[m=lane&15][k=quad*8+j], B^T row = lane&15, D: col=lane&15, row=quad*4+reg.
        const int lane = tid & 63;
        const int w    = tid >> 6;       // wave 0..3
        const int q    = lane >> 4;      // quad 0..3
        const int c    = lane & 15;     // m for A, n for B/D
        const int rowBase = bx * 128;
        const _Float16* Bt = Wt + (size_t)e * 32768;   // [128][256]

        f32x4 acc[2][8];
        #pragma unroll
        for (int mt = 0; mt < 2; ++mt)
            #pragma unroll
            for (int nt = 0; nt < 8; ++nt)
                acc[mt][nt] = (f32x4){0.f, 0.f, 0.f, 0.f};

        int arow[2];
        #pragma unroll
        for (int mt = 0; mt < 2; ++mt) {
            int r = rowBase + w * 32 + mt * 16 + c;
            arow[mt] = (r < N_NODES) ? r : (N_NODES - 1);   // clamp; discarded at store
        }

        #pragma unroll
        for (int ks = 0; ks < 8; ++ks) {           // K = 256 = 8 * 32
            f16x8 afrag[2];
            #pragma unroll
            for (int mt = 0; mt < 2; ++mt) {
                const float* xp = x + (size_t)arow[mt] * 256 + ks * 32 + q * 8;
                f32x4 lo = *(const f32x4*)xp;
                f32x4 hi = *(const f32x4*)(xp + 4);
                f16x8 af;
                #pragma unroll
                for (int j = 0; j < 4; ++j) {
                    af[j]     = (_Float16)lo[j];
                    af[j + 4] = (_Float16)hi[j];
                }
                afrag[mt] = af;
            }
            #pragma unroll
            for (int nt = 0; nt < 8; ++nt) {
                f16x8 bfrag = *(const f16x8*)(Bt + (size_t)(nt * 16 + c) * 256 + ks * 32 + q * 8);
                #pragma unroll
                for (int mt = 0; mt < 2; ++mt)
                    acc[mt][nt] = __builtin_amdgcn_mfma_f32_16x16x32_f16(
                        afrag[mt], bfrag, acc[mt][nt], 0, 0, 0);
            }
        }

        const size_t whBase = (size_t)e * N_NODES * 128;
        #pragma unroll
        for (int nt = 0; nt < 8; ++nt) {
            float bias = b[e * 128 + nt * 16 + c];
            #pragma unroll
            for (int mt = 0; mt < 2; ++mt) {
                int baseRow = rowBase + w * 32 + mt * 16 + q * 4;
                #pragma unroll
                for (int r = 0; r < 4; ++r) {
                    int row = baseRow + r;
                    if (row < N_NODES) {
                        float v = acc[mt][nt][r] + bias;
                        Wh[whBase + (size_t)row * 128 + nt * 16 + c] =
                            __builtin_bit_cast(unsigned short, (_Float16)v);
                    }
                }
            }
        }
    } else {
        // ================= FILL branch (round-8 verified code) =================
        __shared__ int lcnt[NB];
        __shared__ int lbase[NB];
        const int f   = blockIdx.x - GEMM_IDS;     // 0..368
        const int e   = f % 3;
        const int blk = f / 3;
        const int beg = blk * EPB;
        const int* se = src + (size_t)e * N_EDGES;
        const int* de = dst + (size_t)e * N_EDGES;

        for (int j = tid; j < NB; j += 256) lcnt[j] = 0;
        __syncthreads();

        unsigned rec[EPT];
        int      bl [EPT];
        #pragma unroll
        for (int k = 0; k < EPT; ++k) {
            int i = beg + k * 256 + tid;           // coalesced
            if (i < N_EDGES) {
                int s = __builtin_nontemporal_load(se + i);
                int d = __builtin_nontemporal_load(de + i);
                int bb = d >> 6;
                int lpos = atomicAdd(&lcnt[bb], 1);
                rec[k] = (unsigned)s | ((unsigned)(d & 63) << 16);
                bl[k]  = bb | (lpos << 10);        // b<1024 (10b), lpos<8192 (13b)
            } else {
                bl[k] = -1;
            }
        }
        __syncthreads();
        for (int j = tid; j < NB; j += 256) {
            int c = lcnt[j];
            lbase[j] = c ? atomicAdd(&gcur[e * NB + j], c) : 0;
        }
        __syncthreads();
        #pragma unroll
        for (int k = 0; k < EPT; ++k) {
            if (bl[k] >= 0) {
                int bb   = bl[k] & 1023;
                int pos  = lbase[bb] + (bl[k] >> 10);
                if (pos < GCAP)                    // defensive; never trips (+21 sigma)
                    grec[(size_t)(e * NB + bb) * GCAP + pos] = rec[k];
            }
        }
    }
}

// ---------- Fused bucket sort + gather (round-8 code, XCD-partitioned ids) ----
// Round-10 insight: FETCH 315MB == 8 XCDs x full 38.4MB Wh table (every XCD's
// L2 pulled all 3 etype slabs). Now each XCD (bid%8 under rr dispatch) owns a
// CONTIGUOUS ~293-bucket range of the e-major bucket list -> 6 XCDs touch one
// 12.8MB slab, 2 boundary XCDs touch two. Fetch floor 307 -> 128MB; balanced
// VALU (293-294 buckets/XCD). Compute body byte-identical to round-8 control.
__global__ __launch_bounds__(256) void k_bagg(
    const int* __restrict__ cnt_b, const unsigned* __restrict__ grec,
    const unsigned short* __restrict__ Wh, float* __restrict__ out)
{
    __shared__ unsigned       rec_s[GCAP];   // 8 KB
    __shared__ unsigned short nbr_s[GCAP];   // 4 KB
    __shared__ int ndeg[64], ncur[64], nstart[64];
    const int r = blockIdx.x & 7;            // XCD under round-robin dispatch
    const int qq = blockIdx.x >> 3;
    const int cnt_r = (r < 2) ? 294 : 293;
    if (qq >= cnt_r) return;                 // 6 idle blocks of 2352
    const int v  = r * 293 + ((r < 2) ? r : 2) + qq;   // contiguous range per XCD
    const int e  = v / NB;
    const int bx = v - e * NB;
    const int tid  = threadIdx.x;
    const int lane = tid & 63;
    const int w    = tid >> 6;
    const int half = lane >> 5;             // 0: even record, 1: odd record
    const int sub  = lane & 31;
    const int eb   = e * NB + bx;
    const size_t beg = (size_t)eb * GCAP;
    int m = cnt_b[eb];
    if (m > GCAP) m = GCAP;                  // defensive; never trips
    const unsigned* base = (const unsigned*)Wh + (size_t)e * N_NODES * 64; // 64 u32/row

    if (tid < 64) ndeg[tid] = 0;
    __syncthreads();

    // pass 1: stage records + degree histogram (single global read of grec)
    for (int i = tid; i < m; i += 256) {
        unsigned rr_ = __builtin_nontemporal_load(grec + beg + i);
        rec_s[i] = rr_;
        atomicAdd(&ndeg[rr_ >> 16], 1);
    }
    __syncthreads();
    if (tid < 64) {                     // wave 0: exclusive scan of 64 degrees
        int vv = ndeg[tid];
        int s = vv;
        #pragma unroll
        for (int d = 1; d < 64; d <<= 1) {
            int t = __shfl_up(s, d);
            if (tid >= d) s += t;
        }
        int excl = s - vv;
        nstart[tid] = excl;
        ncur[tid]   = excl;
    }
    __syncthreads();
    // pass 2: counting-sort scatter into LDS neighbor list
    for (int i = tid; i < m; i += 256) {
        unsigned rr_ = rec_s[i];
        int p = atomicAdd(&ncur[rr_ >> 16], 1);
        nbr_s[p] = (unsigned short)(rr_ & 0xFFFFu);
    }
    __syncthreads();

    // gather: wave w owns nodes w*16..w*16+15
    for (int t = 0; t < 16; ++t) {
        int node = w * 16 + t;
        int st = nstart[node];
        int dg = ndeg[node];
        float a0 = 0.f, a1 = 0.f, a2 = 0.f, a3 = 0.f;
        for (int c0 = 0; c0 < dg; c0 += 64) {
            int mm = dg - c0; if (mm > 64) mm = 64;
            int idx = (c0 + lane < dg) ? (int)nbr_s[st + c0 + lane] : 0;
            int fullp = mm >> 1;                 // complete pairs
            int p = 0;
            for (; p + 8 <= fullp; p += 8) {     // 16 rows in flight
                uint2 u[8];
                #pragma unroll
                for (int k = 0; k < 8; ++k) {
                    int r0 = 2 * (p + k);
                    int s0 = __builtin_amdgcn_readlane(idx, r0);
                    int s1 = __builtin_amdgcn_readlane(idx, r0 + 1);
                    int s  = half ? s1 : s0;
                    u[k] = *(const uint2*)(base + (size_t)s * 64 + (sub << 1));
                }
                #pragma unroll
                for (int k = 0; k < 8; ++k) {
                    a0 += (float)__builtin_bit_cast(_Float16, (unsigned short)(u[k].x & 0xFFFFu));
                    a1 += (float)__builtin_bit_cast(_Float16, (unsigned short)(u[k].x >> 16));
                    a2 += (float)__builtin_bit_cast(_Float16, (unsigned short)(u[k].y & 0xFFFFu));
                    a3 += (float)__builtin_bit_cast(_Float16, (unsigned short)(u[k].y >> 16));
                }
            }
            if (2 * p < mm) {                    // masked 8-pair tail
                uint2 u[8];
                #pragma unroll
                for (int k = 0; k < 8; ++k) {
                    int r0 = 2 * (p + k);
                    int r0c = (r0     < mm) ? r0     : 0;
                    int r1c = (r0 + 1 < mm) ? r0 + 1 : 0;
                    int s0 = __builtin_amdgcn_readlane(idx, r0c);
                    int s1 = __builtin_amdgcn_readlane(idx, r1c);
                    int s  = half ? s1 : s0;
                    u[k] = *(const uint2*)(base + (size_t)s * 64 + (sub << 1));
                }
                #pragma unroll
                for (int k = 0; k < 8; ++k) {
                    if (2 * (p + k) + half < mm) {
                        a0 += (float)__builtin_bit_cast(_Float16, (unsigned short)(u[k].x & 0xFFFFu));
                        a1 += (float)__builtin_bit_cast(_Float16, (unsigned short)(u[k].x >> 16));
                        a2 += (float)__builtin_bit_cast(_Float16, (unsigned short)(u[k].y & 0xFFFFu));
                        a3 += (float)__builtin_bit_cast(_Float16, (unsigned short)(u[k].y >> 16));
                    }
                }
            }
        }
        // combine even/odd halves: lane L += lane L^32
        a0 += __shfl_xor(a0, 32);
        a1 += __shfl_xor(a1, 32);
        a2 += __shfl_xor(a2, 32);
        a3 += __shfl_xor(a3, 32);
        int n = bx * 64 + node;
        if (half == 0 && n < N_NODES) {
            float inv = (dg > 0) ? (1.0f / (float)dg) : 0.f;
            f32x4 o = {a0 * inv, a1 * inv, a2 * inv, a3 * inv};
            __builtin_nontemporal_store(o, (f32x4*)(out + (size_t)n * 384 + e * 128 + (sub << 2)));
        }
    }
}

// ---------- launch ----------
extern "C" void kernel_launch(void* const* d_in, const int* in_sizes, int n_in,
                              void* d_out, int out_size, void* d_ws, size_t ws_size,
                              hipStream_t stream) {
    const float* x    = (const float*)d_in[0];
    const int*   esrc = (const int*)d_in[1];
    const int*   edst = (const int*)d_in[2];
    const float* W    = (const float*)d_in[3];
    const float* bias = (const float*)d_in[4];
    float*       out  = (float*)d_out;            // fp32 output [N,3,128]

    char* ws = (char*)d_ws;
    _Float16*       Wt  = (_Float16*)ws;                          //    196,608 B
    unsigned short* Wh  = (unsigned short*)(ws + 196608);         // 38,400,000 B
    unsigned* grec = (unsigned*)(ws + 38596608);                  // 19,218,432 B (TOTB*GCAP*4)
    int* gcur      = (int*)(ws + 57815040);                       //      9,472 B

    k_prep_w<<<dim3(128, 3), 256, 0, stream>>>(W, Wt, gcur);
    k_gf<<<GEMM_IDS + FILLB, 256, 0, stream>>>(x, Wt, bias, Wh, esrc, edst, gcur, grec);
    k_bagg<<<2352, 256, 0, stream>>>(gcur, grec, Wh, out);
}